// Round 8
// baseline (666.835 us; speedup 1.0000x reference)
//
#include <hip/hip_runtime.h>
#include <hip/hip_fp16.h>

// ---------------------------------------------------------------------------
// VGAE encoder: two GCN propagations + dense transforms.
// Transform-first: t = x@W1, h = relu(agg(t)+b1), g = h@[Wmu|Wlv],
// [mu|lv] = agg(g)+bias  (agg commutes with the right-multiply).
// Aggregation is column-chunked (16 cols = 3.2MB table slice) so the gather
// table stays L2-resident per XCD; csr stream is nontemporal.
// CSR build uses a two-level counting sort so every scatter window is
// L2-resident (direct random scatter showed 17x write-amp).
// ---------------------------------------------------------------------------

using half8 = __attribute__((ext_vector_type(8))) _Float16;
using f32x4 = __attribute__((ext_vector_type(4))) float;
using f32x2 = __attribute__((ext_vector_type(2))) float;

// Detect whether edge_index arrived as int64 (odd int32 words all zero) or
// int32. Wave-parallel. Writes mode=1 for int64, 0 for int32.
__global__ void detect_kernel(const int* __restrict__ ei, int* __restrict__ mode) {
    int lane = threadIdx.x & 63;
    int any = 0;
    for (int k = lane; k < 1024; k += 64) any |= ei[2 * k + 1];
    unsigned long long b = __ballot(any != 0);
    if (threadIdx.x == 0) *mode = (b == 0ull) ? 1 : 0;
}

__global__ void count_kernel(const int* __restrict__ ei, int E, int n,
                             const int* __restrict__ mode,
                             int* __restrict__ counts) {
    int e = blockIdx.x * blockDim.x + threadIdx.x;
    if (e >= E) return;
    int m = *mode;
    int d = m ? ei[2 * (E + e)] : ei[E + e];
    if ((unsigned)d >= (unsigned)n) return;  // safety
    atomicAdd(&counts[d], 1);
}

// Pass 1: per-block (1024-wide) exclusive scan of counts into row_ptr
// (block-local base), block totals into blk. Also computes dinv.
__global__ __launch_bounds__(1024) void scan1_kernel(
    const int* __restrict__ counts, int* __restrict__ row_ptr,
    int* __restrict__ blk, float* __restrict__ dinv, int n) {
    __shared__ int woff[17];
    int tid = threadIdx.x, lane = tid & 63, wid = tid >> 6;
    int i = blockIdx.x * 1024 + tid;
    int v = (i < n) ? counts[i] : 0;
    if (i < n) dinv[i] = rsqrtf((float)(v + 1));  // +1 self-loop
    int incl = v;
#pragma unroll
    for (int off = 1; off < 64; off <<= 1) {
        int t = __shfl_up(incl, off, 64);
        if (lane >= off) incl += t;
    }
    if (lane == 63) woff[wid + 1] = incl;
    __syncthreads();
    if (tid == 0) {
        int acc = 0;
        woff[0] = 0;
#pragma unroll
        for (int w = 1; w <= 16; ++w) { acc += woff[w]; woff[w] = acc; }
        blk[blockIdx.x] = acc;
    }
    __syncthreads();
    if (i < n) row_ptr[i] = woff[wid] + incl - v;  // block-local exclusive
}

// Pass 2: exclusive scan of nb (<=128) block totals; writes grand total to
// row_ptr_n (= row_ptr + n).
__global__ void scan2_kernel(const int* __restrict__ blk,
                             int* __restrict__ blk_off,
                             int* __restrict__ row_ptr_n, int nb) {
    __shared__ int w0sum;
    int tid = threadIdx.x, lane = tid & 63, wid = tid >> 6;
    int v = (tid < nb) ? blk[tid] : 0;
    int incl = v;
#pragma unroll
    for (int off = 1; off < 64; off <<= 1) {
        int t = __shfl_up(incl, off, 64);
        if (lane >= off) incl += t;
    }
    if (wid == 0 && lane == 63) w0sum = incl;
    __syncthreads();
    int excl = incl - v + (wid ? w0sum : 0);
    if (tid < nb) blk_off[tid] = excl;
    if (tid == nb - 1) *row_ptr_n = excl + v;
}

// Pass 3: add block offsets.
__global__ __launch_bounds__(1024) void scan3_kernel(
    int* __restrict__ row_ptr, const int* __restrict__ blk_off, int n) {
    int i = blockIdx.x * 1024 + threadIdx.x;
    if (i < n) row_ptr[i] += blk_off[blockIdx.x];
}

// Bucket cursors start at each bucket's CSR base (buckets = 256 dst nodes).
__global__ void bucket_base_kernel(const int* __restrict__ row_ptr,
                                   int* __restrict__ cur, int n, int K) {
    int b = blockIdx.x * blockDim.x + threadIdx.x;
    if (b < K) {
        int node = b << 8;
        if (node > n) node = n;
        cur[b] = row_ptr[node];
    }
}

// Partition: LDS-histogram 4096 edges into K buckets, reserve contiguous
// ranges with one global atomic per (block,bucket), write (s,d) pairs
// line-dense into the bucket's region of pair_buf (laid out like the CSR).
__global__ __launch_bounds__(256) void partition_kernel(
    const int* __restrict__ ei, int E, int n, const int* __restrict__ mode,
    int* __restrict__ cur, int2* __restrict__ pairs) {
    __shared__ int hist[512];
    __shared__ int base[512];
    int t = threadIdx.x;
    for (int i = t; i < 512; i += 256) hist[i] = 0;
    __syncthreads();
    int m = *mode;
    int e0 = blockIdx.x * 4096;
    int s_[16], d_[16], o_[16];
#pragma unroll
    for (int k = 0; k < 16; ++k) {
        int e = e0 + k * 256 + t;
        d_[k] = -1;
        if (e < E) {
            int s = m ? ei[2 * e] : ei[e];
            int d = m ? ei[2 * (E + e)] : ei[E + e];
            if ((unsigned)d < (unsigned)n && (unsigned)s < (unsigned)n) {
                s_[k] = s;
                d_[k] = d;
                o_[k] = atomicAdd(&hist[d >> 8], 1);
            }
        }
    }
    __syncthreads();
    int K = (n + 255) >> 8;
    for (int b = t; b < K; b += 256) {
        int h = hist[b];
        base[b] = h ? atomicAdd(&cur[b], h) : 0;
    }
    __syncthreads();
#pragma unroll
    for (int k = 0; k < 16; ++k) {
        if (d_[k] >= 0) {
            int b = d_[k] >> 8;
            pairs[(size_t)(base[b] + o_[k])] = make_int2(s_[k], d_[k]);
        }
    }
}

// Place: one block per bucket; sequential pair read, scatter into the
// bucket's 16KB csr window (+1KB cursor window) -- all L2-resident.
__global__ __launch_bounds__(512) void place_kernel(
    const int2* __restrict__ pairs, const int* __restrict__ row_ptr,
    int* __restrict__ cursor, int* __restrict__ csr_src, int n) {
    int b = blockIdx.x;
    int lo = b << 8, hi = lo + 256;
    if (lo > n) lo = n;
    if (hi > n) hi = n;
    int beg = row_ptr[lo], end = row_ptr[hi];
    for (int i = beg + threadIdx.x; i < end; i += 512) {
        int2 p = pairs[i];
        int pos = atomicAdd(&cursor[p.y], 1);
        csr_src[row_ptr[p.y] + pos] = p.x;
    }
}

// ---------------------------------------------------------------------------
// Column-chunked aggregation. Chunk = 16 cols (32 B fp16) -> table slice
// 3.2 MB, L2-resident per XCD. blockIdx.y = chunk (0..7). Wave handles
// 8 nodes: group g = lane>>3 (node), sublane j = lane&7 (half2 within chunk).
// out = di*(di*T[i] + sum_e dinv[s]*T[s]) + bias[col]
// MODE 0: relu, fp16 out [n x 128] (h).
// MODE 1: f32 split: chunks 0..3 -> outa [n x 64] (mu), 4..7 -> outb (lv).
// ---------------------------------------------------------------------------
template <int MODE>
__global__ __launch_bounds__(256) void agg_chunk_kernel(
    const __half* __restrict__ T, const float* __restrict__ dinv,
    const int* __restrict__ row_ptr, const int* __restrict__ csr_src,
    const float* __restrict__ bias, void* __restrict__ outa,
    void* __restrict__ outb, int n) {
    int c = blockIdx.y;
    int lane = threadIdx.x & 63;
    int g = lane >> 3;
    int j = lane & 7;
    int wave = (int)((blockIdx.x * blockDim.x + threadIdx.x) >> 6);
    int node = wave * 8 + g;
    if (node >= n) return;

    const __half2* x2 = (const __half2*)T;
    size_t colbase = (size_t)c * 8 + j;   // half2 index within 64-half2 row
    float di = dinv[node];
    float2 self = __half22float2(x2[((size_t)node << 6) + colbase]);
    float ax = 0.f, ay = 0.f;
    int e = row_ptr[node], end = row_ptr[node + 1];
    for (; e + 4 <= end; e += 4) {
        int s0 = __builtin_nontemporal_load(csr_src + e + 0);
        int s1 = __builtin_nontemporal_load(csr_src + e + 1);
        int s2 = __builtin_nontemporal_load(csr_src + e + 2);
        int s3 = __builtin_nontemporal_load(csr_src + e + 3);
        float w0 = dinv[s0], w1 = dinv[s1], w2 = dinv[s2], w3 = dinv[s3];
        float2 u0 = __half22float2(x2[((size_t)s0 << 6) + colbase]);
        float2 u1 = __half22float2(x2[((size_t)s1 << 6) + colbase]);
        float2 u2 = __half22float2(x2[((size_t)s2 << 6) + colbase]);
        float2 u3 = __half22float2(x2[((size_t)s3 << 6) + colbase]);
        ax += w0 * u0.x; ay += w0 * u0.y;
        ax += w1 * u1.x; ay += w1 * u1.y;
        ax += w2 * u2.x; ay += w2 * u2.y;
        ax += w3 * u3.x; ay += w3 * u3.y;
    }
    for (; e < end; ++e) {
        int s = __builtin_nontemporal_load(csr_src + e);
        float w = dinv[s];
        float2 u = __half22float2(x2[((size_t)s << 6) + colbase]);
        ax += w * u.x; ay += w * u.y;
    }
    float2 bv = *(const float2*)(bias + c * 16 + 2 * j);
    float vx = di * (di * self.x + ax) + bv.x;
    float vy = di * (di * self.y + ay) + bv.y;
    if (MODE == 0) {
        vx = fmaxf(vx, 0.f);
        vy = fmaxf(vy, 0.f);
        __half2 hv = __floats2half2_rn(vx, vy);
        unsigned int bits;
        __builtin_memcpy(&bits, &hv, 4);
        unsigned int* o = (unsigned int*)outa;
        __builtin_nontemporal_store(bits, o + ((size_t)node << 6) + colbase);
    } else {
        float* o = (c < 4) ? (float*)outa : (float*)outb;
        int cc = (c & 3) * 16 + 2 * j;
        f32x2 v = {vx, vy};
        __builtin_nontemporal_store(v, (f32x2*)(o + (size_t)node * 64 + cc));
    }
}

// ---------------------------------------------------------------------------
// Pack f32 weights into fp16 MFMA B-fragment order.
// b_frag for (nt,kt) at lane l must hold B[k][c] for
//   k = kt*32 + (l>>4)*8 + e  (e=0..7),  c = nt*16 + (l&15).
// Wb == nullptr: single 128-col matrix Wa (ld 128).
// Wb != nullptr: cols 0..63 from Wa, 64..127 from Wb (each ld 64).
// ---------------------------------------------------------------------------
__global__ void packw_kernel(const float* __restrict__ Wa,
                             const float* __restrict__ Wb,
                             __half* __restrict__ dst) {
    int t = blockIdx.x * 256 + threadIdx.x;   // 0..2047
    int lane = t & 63;
    int fk = t >> 6;          // nt*4 + kt
    int kt = fk & 3, nt = fk >> 2;
    int k0 = kt * 32 + ((lane >> 4) << 3);
    int c = nt * 16 + (lane & 15);
    const float* W;
    int ldw, cc;
    if (Wb) {
        W = (c < 64) ? Wa : Wb;
        cc = c & 63;
        ldw = 64;
    } else {
        W = Wa;
        cc = c;
        ldw = 128;
    }
    __half tmp[8];
#pragma unroll
    for (int e = 0; e < 8; ++e)
        tmp[e] = __float2half(W[(size_t)(k0 + e) * ldw + cc]);
    *(float4*)(dst + (size_t)t * 8) = *(float4*)tmp;
}

__global__ void packb_kernel(const float* __restrict__ bmu,
                             const float* __restrict__ blv,
                             float* __restrict__ bcomb) {
    int i = threadIdx.x;  // 128
    bcomb[i] = (i < 64) ? bmu[i] : blv[i - 64];
}

// ---------------------------------------------------------------------------
// Pure MFMA GEMM (no bias/relu): A [n x 128] (f32 or fp16) @ packed Wp
// -> fp16 out [n x 128]. 4 waves/block, 16-row strip per wave.
// A-frag: lane holds row (lane&15), k = kt*32 + (lane>>4)*8 + e
// C-frag: col = lane&15, row = (lane>>4)*4 + reg   (m89-verified)
// ---------------------------------------------------------------------------
template <typename AT>
__global__ __launch_bounds__(256) void gemm_pure_kernel(
    const AT* __restrict__ A, const __half* __restrict__ Wp,
    __half* __restrict__ outh, int n) {
    int lane = threadIdx.x & 63;
    int wv = threadIdx.x >> 6;
    int m0 = (blockIdx.x * 4 + wv) * 16;
    if (m0 >= n) return;
    int row_a = m0 + (lane & 15);
    if (row_a >= n) row_a = n - 1;              // clamp; stores guarded
    half8 afr[4];
    if constexpr (sizeof(AT) == 4) {
        const float4* Arow = (const float4*)(A + (size_t)row_a * 128);
#pragma unroll
        for (int kt = 0; kt < 4; ++kt) {
            float4 lo = Arow[kt * 8 + ((lane >> 4) << 1)];
            float4 hi = Arow[kt * 8 + ((lane >> 4) << 1) + 1];
            half8 h;
            h[0] = (_Float16)lo.x; h[1] = (_Float16)lo.y;
            h[2] = (_Float16)lo.z; h[3] = (_Float16)lo.w;
            h[4] = (_Float16)hi.x; h[5] = (_Float16)hi.y;
            h[6] = (_Float16)hi.z; h[7] = (_Float16)hi.w;
            afr[kt] = h;
        }
    } else {
        const half8* Arow = (const half8*)(A + (size_t)row_a * 128);
#pragma unroll
        for (int kt = 0; kt < 4; ++kt) afr[kt] = Arow[kt * 4 + (lane >> 4)];
    }

    const half8* Wf = (const half8*)Wp;
    int colw = lane & 15;
    int rbase = m0 + ((lane >> 4) << 2);

#pragma unroll
    for (int nt = 0; nt < 8; ++nt) {
        f32x4 acc = {0.f, 0.f, 0.f, 0.f};
#pragma unroll
        for (int kt = 0; kt < 4; ++kt)
            acc = __builtin_amdgcn_mfma_f32_16x16x32_f16(
                afr[kt], Wf[(nt * 4 + kt) * 64 + lane], acc, 0, 0, 0);
        int c = nt * 16 + colw;
#pragma unroll
        for (int e = 0; e < 4; ++e) {
            int r = rbase + e;
            if (r < n) outh[(size_t)r * 128 + c] = __float2half(acc[e]);
        }
    }
}

extern "C" void kernel_launch(void* const* d_in, const int* in_sizes, int n_in,
                              void* d_out, int out_size, void* d_ws, size_t ws_size,
                              hipStream_t stream) {
    const float* x   = (const float*)d_in[0];
    const int*   ei  = (const int*)d_in[1];
    const float* W1  = (const float*)d_in[2];
    const float* b1  = (const float*)d_in[3];
    const float* Wmu = (const float*)d_in[4];
    const float* bmu = (const float*)d_in[5];
    const float* Wlv = (const float*)d_in[6];
    const float* blv = (const float*)d_in[7];
    float* out = (float*)d_out;

    const int n = in_sizes[0] / 128;   // 100000
    const int E = in_sizes[1] / 2;     // 1600000
    const int nb = (n + 1023) / 1024;  // scan blocks (98)
    const int K  = (n + 255) >> 8;     // dst buckets (391)

    char* ws = (char*)d_ws;
    size_t off = 0;
    auto alloc = [&](size_t bytes) -> void* {
        void* p = ws + off;
        off += (bytes + 255) & ~(size_t)255;
        return p;
    };
    int*   mode    = (int*)alloc(256);
    int*   counts  = (int*)alloc((size_t)n * 4);
    int*   cursor  = (int*)alloc((size_t)n * 4);
    int*   row_ptr = (int*)alloc((size_t)(n + 1) * 4);
    int*   blk     = (int*)alloc((size_t)nb * 4);
    int*   blk_off = (int*)alloc((size_t)nb * 4);
    int*   bcur    = (int*)alloc((size_t)K * 4);
    float* dinv    = (float*)alloc((size_t)n * 4);
    int*   csr_src = (int*)alloc((size_t)E * 4);
    int2*  pairs   = (int2*)alloc((size_t)E * 8);
    __half* bufT   = (__half*)alloc((size_t)n * 128 * 2);  // t, then g
    __half* bufH   = (__half*)alloc((size_t)n * 128 * 2);  // h
    __half* W1p    = (__half*)alloc(128 * 128 * 2);        // packed W1
    __half* W2p    = (__half*)alloc(128 * 128 * 2);        // packed [Wmu|Wlv]
    float* bcomb   = (float*)alloc(128 * 4);               // [bmu|blv]

    hipMemsetAsync(counts, 0, (size_t)n * 4, stream);
    hipMemsetAsync(cursor, 0, (size_t)n * 4, stream);

    detect_kernel<<<1, 64, 0, stream>>>(ei, mode);

    int eb = (E + 255) / 256;
    count_kernel<<<eb, 256, 0, stream>>>(ei, E, n, mode, counts);
    scan1_kernel<<<nb, 1024, 0, stream>>>(counts, row_ptr, blk, dinv, n);
    scan2_kernel<<<1, 128, 0, stream>>>(blk, blk_off, row_ptr + n, nb);
    scan3_kernel<<<nb, 1024, 0, stream>>>(row_ptr, blk_off, n);

    // CSR build: bucket partition (line-dense writes) + L2-local place.
    bucket_base_kernel<<<(K + 255) / 256, 256, 0, stream>>>(row_ptr, bcur, n, K);
    partition_kernel<<<(E + 4095) / 4096, 256, 0, stream>>>(ei, E, n, mode,
                                                            bcur, pairs);
    place_kernel<<<K, 512, 0, stream>>>(pairs, row_ptr, cursor, csr_src, n);

    // Weight packing (tiny)
    packw_kernel<<<8, 256, 0, stream>>>(W1, nullptr, W1p);
    packw_kernel<<<8, 256, 0, stream>>>(Wmu, Wlv, W2p);
    packb_kernel<<<1, 128, 0, stream>>>(bmu, blv, bcomb);

    int gb = (n + 63) / 64;                 // MFMA gemm blocks
    dim3 ag((n + 31) / 32, 8);              // chunked agg: 32 nodes/block x 8

    // t = x @ W1  (f32 A -> fp16)
    gemm_pure_kernel<float><<<gb, 256, 0, stream>>>(x, W1p, bufT, n);
    // h = relu(agg(t) + b1)  (fp16)
    agg_chunk_kernel<0><<<ag, 256, 0, stream>>>(bufT, dinv, row_ptr, csr_src,
                                                b1, bufH, nullptr, n);
    // g = h @ [Wmu|Wlv]  (fp16)
    gemm_pure_kernel<__half><<<gb, 256, 0, stream>>>(bufH, W2p, bufT, n);
    // mu / logvar = agg(g) + bias  (f32 slabs)
    agg_chunk_kernel<1><<<ag, 256, 0, stream>>>(bufT, dinv, row_ptr, csr_src,
                                                bcomb, out, out + (size_t)n * 64, n);
}

// Round 9
// 602.527 us; speedup vs baseline: 1.1067x; 1.1067x over previous
//
#include <hip/hip_runtime.h>
#include <hip/hip_fp16.h>

// ---------------------------------------------------------------------------
// VGAE encoder: two GCN propagations + dense transforms.
// Transform-first: t = x@W1, h = relu(agg(t)+b1), g = h@[Wmu|Wlv],
// [mu|lv] = agg(g)+bias  (agg commutes with the right-multiply).
// Feature matrices t,h,g are stored CHUNK-MAJOR: T[c][node][16 cols] fp16,
// so each 16-col chunk is a physically contiguous 3.2MB slice. Aggregation
// assigns chunk c to XCD c via (blockIdx.x & 7) -> each XCD's 4MiB L2 holds
// exactly one slice; gathers become L2 hits. csr is streamed nontemporal.
// CSR build uses a two-level counting sort so every scatter window is
// L2-resident (direct random scatter showed 17x write-amp).
// ---------------------------------------------------------------------------

using half8 = __attribute__((ext_vector_type(8))) _Float16;
using f32x4 = __attribute__((ext_vector_type(4))) float;
using f32x2 = __attribute__((ext_vector_type(2))) float;

// Detect whether edge_index arrived as int64 (odd int32 words all zero) or
// int32. Wave-parallel. Writes mode=1 for int64, 0 for int32.
__global__ void detect_kernel(const int* __restrict__ ei, int* __restrict__ mode) {
    int lane = threadIdx.x & 63;
    int any = 0;
    for (int k = lane; k < 1024; k += 64) any |= ei[2 * k + 1];
    unsigned long long b = __ballot(any != 0);
    if (threadIdx.x == 0) *mode = (b == 0ull) ? 1 : 0;
}

__global__ void count_kernel(const int* __restrict__ ei, int E, int n,
                             const int* __restrict__ mode,
                             int* __restrict__ counts) {
    int e = blockIdx.x * blockDim.x + threadIdx.x;
    if (e >= E) return;
    int m = *mode;
    int d = m ? ei[2 * (E + e)] : ei[E + e];
    if ((unsigned)d >= (unsigned)n) return;  // safety
    atomicAdd(&counts[d], 1);
}

// Pass 1: per-block (1024-wide) exclusive scan of counts into row_ptr
// (block-local base), block totals into blk. Also computes dinv.
__global__ __launch_bounds__(1024) void scan1_kernel(
    const int* __restrict__ counts, int* __restrict__ row_ptr,
    int* __restrict__ blk, float* __restrict__ dinv, int n) {
    __shared__ int woff[17];
    int tid = threadIdx.x, lane = tid & 63, wid = tid >> 6;
    int i = blockIdx.x * 1024 + tid;
    int v = (i < n) ? counts[i] : 0;
    if (i < n) dinv[i] = rsqrtf((float)(v + 1));  // +1 self-loop
    int incl = v;
#pragma unroll
    for (int off = 1; off < 64; off <<= 1) {
        int t = __shfl_up(incl, off, 64);
        if (lane >= off) incl += t;
    }
    if (lane == 63) woff[wid + 1] = incl;
    __syncthreads();
    if (tid == 0) {
        int acc = 0;
        woff[0] = 0;
#pragma unroll
        for (int w = 1; w <= 16; ++w) { acc += woff[w]; woff[w] = acc; }
        blk[blockIdx.x] = acc;
    }
    __syncthreads();
    if (i < n) row_ptr[i] = woff[wid] + incl - v;  // block-local exclusive
}

// Pass 2: exclusive scan of nb (<=128) block totals; writes grand total to
// row_ptr_n (= row_ptr + n).
__global__ void scan2_kernel(const int* __restrict__ blk,
                             int* __restrict__ blk_off,
                             int* __restrict__ row_ptr_n, int nb) {
    __shared__ int w0sum;
    int tid = threadIdx.x, lane = tid & 63, wid = tid >> 6;
    int v = (tid < nb) ? blk[tid] : 0;
    int incl = v;
#pragma unroll
    for (int off = 1; off < 64; off <<= 1) {
        int t = __shfl_up(incl, off, 64);
        if (lane >= off) incl += t;
    }
    if (wid == 0 && lane == 63) w0sum = incl;
    __syncthreads();
    int excl = incl - v + (wid ? w0sum : 0);
    if (tid < nb) blk_off[tid] = excl;
    if (tid == nb - 1) *row_ptr_n = excl + v;
}

// Pass 3: add block offsets.
__global__ __launch_bounds__(1024) void scan3_kernel(
    int* __restrict__ row_ptr, const int* __restrict__ blk_off, int n) {
    int i = blockIdx.x * 1024 + threadIdx.x;
    if (i < n) row_ptr[i] += blk_off[blockIdx.x];
}

// Bucket cursors start at each bucket's CSR base (buckets = 256 dst nodes).
__global__ void bucket_base_kernel(const int* __restrict__ row_ptr,
                                   int* __restrict__ cur, int n, int K) {
    int b = blockIdx.x * blockDim.x + threadIdx.x;
    if (b < K) {
        int node = b << 8;
        if (node > n) node = n;
        cur[b] = row_ptr[node];
    }
}

// Partition: LDS-histogram 4096 edges into K buckets, reserve contiguous
// ranges with one global atomic per (block,bucket), write (s,d) pairs
// line-dense into the bucket's region of pair_buf (laid out like the CSR).
__global__ __launch_bounds__(256) void partition_kernel(
    const int* __restrict__ ei, int E, int n, const int* __restrict__ mode,
    int* __restrict__ cur, int2* __restrict__ pairs) {
    __shared__ int hist[512];
    __shared__ int base[512];
    int t = threadIdx.x;
    for (int i = t; i < 512; i += 256) hist[i] = 0;
    __syncthreads();
    int m = *mode;
    int e0 = blockIdx.x * 4096;
    int s_[16], d_[16], o_[16];
#pragma unroll
    for (int k = 0; k < 16; ++k) {
        int e = e0 + k * 256 + t;
        d_[k] = -1;
        if (e < E) {
            int s = m ? ei[2 * e] : ei[e];
            int d = m ? ei[2 * (E + e)] : ei[E + e];
            if ((unsigned)d < (unsigned)n && (unsigned)s < (unsigned)n) {
                s_[k] = s;
                d_[k] = d;
                o_[k] = atomicAdd(&hist[d >> 8], 1);
            }
        }
    }
    __syncthreads();
    int K = (n + 255) >> 8;
    for (int b = t; b < K; b += 256) {
        int h = hist[b];
        base[b] = h ? atomicAdd(&cur[b], h) : 0;
    }
    __syncthreads();
#pragma unroll
    for (int k = 0; k < 16; ++k) {
        if (d_[k] >= 0) {
            int b = d_[k] >> 8;
            pairs[(size_t)(base[b] + o_[k])] = make_int2(s_[k], d_[k]);
        }
    }
}

// Place: one block per bucket; sequential pair read, scatter into the
// bucket's 16KB csr window (+1KB cursor window) -- all L2-resident.
__global__ __launch_bounds__(512) void place_kernel(
    const int2* __restrict__ pairs, const int* __restrict__ row_ptr,
    int* __restrict__ cursor, int* __restrict__ csr_src, int n) {
    int b = blockIdx.x;
    int lo = b << 8, hi = lo + 256;
    if (lo > n) lo = n;
    if (hi > n) hi = n;
    int beg = row_ptr[lo], end = row_ptr[hi];
    for (int i = beg + threadIdx.x; i < end; i += 512) {
        int2 p = pairs[i];
        int pos = atomicAdd(&cursor[p.y], 1);
        csr_src[row_ptr[p.y] + pos] = p.x;
    }
}

// ---------------------------------------------------------------------------
// XCD-affine column-chunked aggregation over chunk-major features.
// T layout: T[c][node][16 cols] fp16; slice c is contiguous 3.2MB.
// chunk = blockIdx.x & 7  -> round-robin dispatch puts chunk c on XCD c,
// whose L2 then holds only that slice (L2-resident gathers).
// Wave handles 8 nodes: g = lane>>3 (node), j = lane&7 (half2 in chunk).
// out = di*(di*T[i] + sum_e dinv[s]*T[s]) + bias[col]
// MODE 0: relu, fp16 chunk-major out (h).
// MODE 1: f32 split row-major: chunks 0..3 -> outa [n x 64] (mu), 4..7 -> outb.
// ---------------------------------------------------------------------------
template <int MODE>
__global__ __launch_bounds__(256) void agg_chunk_kernel(
    const __half* __restrict__ T, const float* __restrict__ dinv,
    const int* __restrict__ row_ptr, const int* __restrict__ csr_src,
    const float* __restrict__ bias, void* __restrict__ outa,
    void* __restrict__ outb, int n) {
    int bid = blockIdx.x;
    int c = bid & 7;              // chunk -> XCD (round-robin heuristic)
    int nodeblk = bid >> 3;
    int lane = threadIdx.x & 63;
    int wv = threadIdx.x >> 6;
    int g = lane >> 3;
    int j = lane & 7;
    int node = nodeblk * 32 + wv * 8 + g;
    if (node >= n) return;

    const __half2* x2 = (const __half2*)T + (size_t)c * n * 8;  // slice base
    float di = dinv[node];
    float2 self = __half22float2(x2[(size_t)node * 8 + j]);
    float ax = 0.f, ay = 0.f;
    int e = row_ptr[node], end = row_ptr[node + 1];
    for (; e + 8 <= end; e += 8) {
        int s[8];
        float w[8];
        float2 u[8];
#pragma unroll
        for (int k = 0; k < 8; ++k)
            s[k] = __builtin_nontemporal_load(csr_src + e + k);
#pragma unroll
        for (int k = 0; k < 8; ++k)
            u[k] = __half22float2(x2[(size_t)s[k] * 8 + j]);
#pragma unroll
        for (int k = 0; k < 8; ++k) w[k] = dinv[s[k]];
#pragma unroll
        for (int k = 0; k < 8; ++k) {
            ax += w[k] * u[k].x;
            ay += w[k] * u[k].y;
        }
    }
    for (; e < end; ++e) {
        int s = __builtin_nontemporal_load(csr_src + e);
        float w = dinv[s];
        float2 u = __half22float2(x2[(size_t)s * 8 + j]);
        ax += w * u.x;
        ay += w * u.y;
    }
    float2 bv = *(const float2*)(bias + c * 16 + 2 * j);
    float vx = di * (di * self.x + ax) + bv.x;
    float vy = di * (di * self.y + ay) + bv.y;
    if (MODE == 0) {
        vx = fmaxf(vx, 0.f);
        vy = fmaxf(vy, 0.f);
        __half2 hv = __floats2half2_rn(vx, vy);
        unsigned int bits;
        __builtin_memcpy(&bits, &hv, 4);
        unsigned int* o = (unsigned int*)outa;  // chunk-major h
        __builtin_nontemporal_store(bits, o + ((size_t)c * n + node) * 8 + j);
    } else {
        float* o = (c < 4) ? (float*)outa : (float*)outb;
        int cc = (c & 3) * 16 + 2 * j;
        f32x2 v = {vx, vy};
        __builtin_nontemporal_store(v, (f32x2*)(o + (size_t)node * 64 + cc));
    }
}

// ---------------------------------------------------------------------------
// Pack f32 weights into fp16 MFMA B-fragment order.
// b_frag for (nt,kt) at lane l must hold B[k][c] for
//   k = kt*32 + (l>>4)*8 + e  (e=0..7),  c = nt*16 + (l&15).
// Wb == nullptr: single 128-col matrix Wa (ld 128).
// Wb != nullptr: cols 0..63 from Wa, 64..127 from Wb (each ld 64).
// ---------------------------------------------------------------------------
__global__ void packw_kernel(const float* __restrict__ Wa,
                             const float* __restrict__ Wb,
                             __half* __restrict__ dst) {
    int t = blockIdx.x * 256 + threadIdx.x;   // 0..2047
    int lane = t & 63;
    int fk = t >> 6;          // nt*4 + kt
    int kt = fk & 3, nt = fk >> 2;
    int k0 = kt * 32 + ((lane >> 4) << 3);
    int c = nt * 16 + (lane & 15);
    const float* W;
    int ldw, cc;
    if (Wb) {
        W = (c < 64) ? Wa : Wb;
        cc = c & 63;
        ldw = 64;
    } else {
        W = Wa;
        cc = c;
        ldw = 128;
    }
    __half tmp[8];
#pragma unroll
    for (int e = 0; e < 8; ++e)
        tmp[e] = __float2half(W[(size_t)(k0 + e) * ldw + cc]);
    *(float4*)(dst + (size_t)t * 8) = *(float4*)tmp;
}

__global__ void packb_kernel(const float* __restrict__ bmu,
                             const float* __restrict__ blv,
                             float* __restrict__ bcomb) {
    int i = threadIdx.x;  // 128
    bcomb[i] = (i < 64) ? bmu[i] : blv[i - 64];
}

// ---------------------------------------------------------------------------
// Pure MFMA GEMM (no bias/relu): A [n x 128] @ packed Wp -> fp16 out,
// CHUNK-MAJOR: out[c][node][16]. 4 waves/block, 16-row strip per wave.
// A: f32 row-major (AT=float) or fp16 chunk-major (AT=__half).
// A-frag: lane holds row (lane&15), k = kt*32 + (lane>>4)*8 + e
// C-frag: col = lane&15, row = (lane>>4)*4 + reg   (m89-verified)
// ---------------------------------------------------------------------------
template <typename AT>
__global__ __launch_bounds__(256) void gemm_pure_kernel(
    const AT* __restrict__ A, const __half* __restrict__ Wp,
    __half* __restrict__ outh, int n) {
    int lane = threadIdx.x & 63;
    int wv = threadIdx.x >> 6;
    int m0 = (blockIdx.x * 4 + wv) * 16;
    if (m0 >= n) return;
    int row_a = m0 + (lane & 15);
    if (row_a >= n) row_a = n - 1;              // clamp; stores guarded
    half8 afr[4];
    if constexpr (sizeof(AT) == 4) {
        // f32 row-major (the input x)
        const float4* Arow = (const float4*)(A + (size_t)row_a * 128);
#pragma unroll
        for (int kt = 0; kt < 4; ++kt) {
            float4 lo = Arow[kt * 8 + ((lane >> 4) << 1)];
            float4 hi = Arow[kt * 8 + ((lane >> 4) << 1) + 1];
            half8 h;
            h[0] = (_Float16)lo.x; h[1] = (_Float16)lo.y;
            h[2] = (_Float16)lo.z; h[3] = (_Float16)lo.w;
            h[4] = (_Float16)hi.x; h[5] = (_Float16)hi.y;
            h[6] = (_Float16)hi.z; h[7] = (_Float16)hi.w;
            afr[kt] = h;
        }
    } else {
        // fp16 chunk-major: 8-half fragment lies inside one 16-col chunk
#pragma unroll
        for (int kt = 0; kt < 4; ++kt) {
            int k0 = kt * 32 + ((lane >> 4) << 3);
            afr[kt] = *(const half8*)((const __half*)A +
                      ((size_t)(k0 >> 4) * n + row_a) * 16 + (k0 & 15));
        }
    }

    const half8* Wf = (const half8*)Wp;
    int colw = lane & 15;
    int rbase = m0 + ((lane >> 4) << 2);

#pragma unroll
    for (int nt = 0; nt < 8; ++nt) {
        f32x4 acc = {0.f, 0.f, 0.f, 0.f};
#pragma unroll
        for (int kt = 0; kt < 4; ++kt)
            acc = __builtin_amdgcn_mfma_f32_16x16x32_f16(
                afr[kt], Wf[(nt * 4 + kt) * 64 + lane], acc, 0, 0, 0);
        // chunk-major store: chunk = nt
#pragma unroll
        for (int e = 0; e < 4; ++e) {
            int r = rbase + e;
            if (r < n)
                outh[((size_t)nt * n + r) * 16 + colw] = __float2half(acc[e]);
        }
    }
}

extern "C" void kernel_launch(void* const* d_in, const int* in_sizes, int n_in,
                              void* d_out, int out_size, void* d_ws, size_t ws_size,
                              hipStream_t stream) {
    const float* x   = (const float*)d_in[0];
    const int*   ei  = (const int*)d_in[1];
    const float* W1  = (const float*)d_in[2];
    const float* b1  = (const float*)d_in[3];
    const float* Wmu = (const float*)d_in[4];
    const float* bmu = (const float*)d_in[5];
    const float* Wlv = (const float*)d_in[6];
    const float* blv = (const float*)d_in[7];
    float* out = (float*)d_out;

    const int n = in_sizes[0] / 128;   // 100000
    const int E = in_sizes[1] / 2;     // 1600000
    const int nb = (n + 1023) / 1024;  // scan blocks (98)
    const int K  = (n + 255) >> 8;     // dst buckets (391)

    char* ws = (char*)d_ws;
    size_t off = 0;
    auto alloc = [&](size_t bytes) -> void* {
        void* p = ws + off;
        off += (bytes + 255) & ~(size_t)255;
        return p;
    };
    int*   mode    = (int*)alloc(256);
    int*   counts  = (int*)alloc((size_t)n * 4);
    int*   cursor  = (int*)alloc((size_t)n * 4);
    int*   row_ptr = (int*)alloc((size_t)(n + 1) * 4);
    int*   blk     = (int*)alloc((size_t)nb * 4);
    int*   blk_off = (int*)alloc((size_t)nb * 4);
    int*   bcur    = (int*)alloc((size_t)K * 4);
    float* dinv    = (float*)alloc((size_t)n * 4);
    int*   csr_src = (int*)alloc((size_t)E * 4);
    int2*  pairs   = (int2*)alloc((size_t)E * 8);
    __half* bufT   = (__half*)alloc((size_t)n * 128 * 2);  // t, then g (chunk-major)
    __half* bufH   = (__half*)alloc((size_t)n * 128 * 2);  // h (chunk-major)
    __half* W1p    = (__half*)alloc(128 * 128 * 2);        // packed W1
    __half* W2p    = (__half*)alloc(128 * 128 * 2);        // packed [Wmu|Wlv]
    float* bcomb   = (float*)alloc(128 * 4);               // [bmu|blv]

    hipMemsetAsync(counts, 0, (size_t)n * 4, stream);
    hipMemsetAsync(cursor, 0, (size_t)n * 4, stream);

    detect_kernel<<<1, 64, 0, stream>>>(ei, mode);

    int eb = (E + 255) / 256;
    count_kernel<<<eb, 256, 0, stream>>>(ei, E, n, mode, counts);
    scan1_kernel<<<nb, 1024, 0, stream>>>(counts, row_ptr, blk, dinv, n);
    scan2_kernel<<<1, 128, 0, stream>>>(blk, blk_off, row_ptr + n, nb);
    scan3_kernel<<<nb, 1024, 0, stream>>>(row_ptr, blk_off, n);

    // CSR build: bucket partition (line-dense writes) + L2-local place.
    bucket_base_kernel<<<(K + 255) / 256, 256, 0, stream>>>(row_ptr, bcur, n, K);
    partition_kernel<<<(E + 4095) / 4096, 256, 0, stream>>>(ei, E, n, mode,
                                                            bcur, pairs);
    place_kernel<<<K, 512, 0, stream>>>(pairs, row_ptr, cursor, csr_src, n);

    // Weight packing (tiny)
    packw_kernel<<<8, 256, 0, stream>>>(W1, nullptr, W1p);
    packw_kernel<<<8, 256, 0, stream>>>(Wmu, Wlv, W2p);
    packb_kernel<<<1, 128, 0, stream>>>(bmu, blv, bcomb);

    int gb = (n + 63) / 64;                 // MFMA gemm blocks
    int agBlocks = ((n + 31) / 32) * 8;     // XCD-affine chunked agg

    // t = x @ W1  (f32 row-major A -> fp16 chunk-major)
    gemm_pure_kernel<float><<<gb, 256, 0, stream>>>(x, W1p, bufT, n);
    // h = relu(agg(t) + b1)  (chunk-major fp16)
    agg_chunk_kernel<0><<<agBlocks, 256, 0, stream>>>(bufT, dinv, row_ptr,
                                                      csr_src, b1, bufH,
                                                      nullptr, n);
    // g = h @ [Wmu|Wlv]  (chunk-major fp16)
    gemm_pure_kernel<__half><<<gb, 256, 0, stream>>>(bufH, W2p, bufT, n);
    // mu / logvar = agg(g) + bias  (f32 row-major slabs)
    agg_chunk_kernel<1><<<agBlocks, 256, 0, stream>>>(bufT, dinv, row_ptr,
                                                      csr_src, bcomb, out,
                                                      out + (size_t)n * 64, n);
}

// Round 10
// 260.366 us; speedup vs baseline: 2.5611x; 2.3142x over previous
//
#include <hip/hip_runtime.h>
#include <hip/hip_fp16.h>

// ---------------------------------------------------------------------------
// VGAE encoder: two GCN propagations + dense transforms.
// Transform-first: t = x@W1, h = relu(agg(t)+b1), g = h@[Wmu|Wlv],
// [mu|lv] = agg(g)+bias  (agg commutes with the right-multiply).
// agg is MONOLITHIC row-gather (256B/edge, 2 cache lines): column-chunked
// variants lose 3x on L1 line-request rate (32B/lane-group = 8 lines/instr).
// CSR build: bucket-count (391 totals) -> scan -> partition into bucket
// regions -> fused build (LDS hist+scan -> row_ptr, dinv, place via LDS
// cursors). No per-node global atomics, every scatter window L2-local.
// ---------------------------------------------------------------------------

using half8 = __attribute__((ext_vector_type(8))) _Float16;
using f32x4 = __attribute__((ext_vector_type(4))) float;
using f32x2 = __attribute__((ext_vector_type(2))) float;

// Detect whether edge_index arrived as int64 (odd int32 words all zero) or
// int32. Wave-parallel. Writes mode=1 for int64, 0 for int32.
__global__ void detect_kernel(const int* __restrict__ ei, int* __restrict__ mode) {
    int lane = threadIdx.x & 63;
    int any = 0;
    for (int k = lane; k < 1024; k += 64) any |= ei[2 * k + 1];
    unsigned long long b = __ballot(any != 0);
    if (threadIdx.x == 0) *mode = (b == 0ull) ? 1 : 0;
}

// Count edges per 256-node dst bucket (K buckets) via LDS histogram.
// Validity predicate MUST match partition_kernel exactly.
__global__ __launch_bounds__(256) void bucket_count_kernel(
    const int* __restrict__ ei, int E, int n, const int* __restrict__ mode,
    int* __restrict__ bcnt) {
    __shared__ int h[512];
    int t = threadIdx.x;
    for (int i = t; i < 512; i += 256) h[i] = 0;
    __syncthreads();
    int m = *mode;
    int e0 = blockIdx.x * 4096;
#pragma unroll
    for (int k = 0; k < 16; ++k) {
        int e = e0 + k * 256 + t;
        if (e < E) {
            int s = m ? ei[2 * e] : ei[e];
            int d = m ? ei[2 * (E + e)] : ei[E + e];
            if ((unsigned)d < (unsigned)n && (unsigned)s < (unsigned)n)
                atomicAdd(&h[d >> 8], 1);
        }
    }
    __syncthreads();
    int K = (n + 255) >> 8;
    for (int b = t; b < K; b += 256)
        if (h[b]) atomicAdd(&bcnt[b], h[b]);
}

// Exclusive scan of K (<=512) bucket counts -> bbase[0..K], partition
// cursors cur[], and row_ptr[n] (grand total).
__global__ __launch_bounds__(512) void bucket_scan_kernel(
    const int* __restrict__ bcnt, int* __restrict__ bbase,
    int* __restrict__ cur, int* __restrict__ row_ptr_n, int K) {
    __shared__ int wtot[8];
    int tid = threadIdx.x, lane = tid & 63, wv = tid >> 6;
    int v = (tid < K) ? bcnt[tid] : 0;
    int incl = v;
#pragma unroll
    for (int off = 1; off < 64; off <<= 1) {
        int t = __shfl_up(incl, off, 64);
        if (lane >= off) incl += t;
    }
    if (lane == 63) wtot[wv] = incl;
    __syncthreads();
    int wo = 0;
    for (int w = 0; w < wv; ++w) wo += wtot[w];
    int ex = wo + incl - v;
    if (tid < K) {
        bbase[tid] = ex;
        cur[tid] = ex;
    }
    if (tid == K - 1) {
        bbase[K] = ex + v;
        *row_ptr_n = ex + v;
    }
}

// Partition: LDS-histogram 4096 edges into K buckets, reserve contiguous
// ranges with one global atomic per (block,bucket), write (s,d) pairs
// line-dense into the bucket's region of pairs.
__global__ __launch_bounds__(256) void partition_kernel(
    const int* __restrict__ ei, int E, int n, const int* __restrict__ mode,
    int* __restrict__ cur, int2* __restrict__ pairs) {
    __shared__ int hist[512];
    __shared__ int base[512];
    int t = threadIdx.x;
    for (int i = t; i < 512; i += 256) hist[i] = 0;
    __syncthreads();
    int m = *mode;
    int e0 = blockIdx.x * 4096;
    int s_[16], d_[16], o_[16];
#pragma unroll
    for (int k = 0; k < 16; ++k) {
        int e = e0 + k * 256 + t;
        d_[k] = -1;
        if (e < E) {
            int s = m ? ei[2 * e] : ei[e];
            int d = m ? ei[2 * (E + e)] : ei[E + e];
            if ((unsigned)d < (unsigned)n && (unsigned)s < (unsigned)n) {
                s_[k] = s;
                d_[k] = d;
                o_[k] = atomicAdd(&hist[d >> 8], 1);
            }
        }
    }
    __syncthreads();
    int K = (n + 255) >> 8;
    for (int b = t; b < K; b += 256) {
        int h = hist[b];
        base[b] = h ? atomicAdd(&cur[b], h) : 0;
    }
    __syncthreads();
#pragma unroll
    for (int k = 0; k < 16; ++k) {
        if (d_[k] >= 0) {
            int b = d_[k] >> 8;
            pairs[(size_t)(base[b] + o_[k])] = make_int2(s_[k], d_[k]);
        }
    }
}

// Fused CSR build, one block per bucket: LDS histogram of the bucket's
// pairs -> LDS scan -> row_ptr + dinv for the 256-node range, then place
// csr_src via LDS cursors. All global windows (32KB pairs, 16KB csr,
// 1KB row_ptr/dinv) are L2-local.
__global__ __launch_bounds__(256) void build_kernel(
    const int2* __restrict__ pairs, const int* __restrict__ bbase,
    int* __restrict__ row_ptr, float* __restrict__ dinv,
    int* __restrict__ csr_src, int n) {
    __shared__ int hist[256];
    __shared__ int wtot[4];
    int b = blockIdx.x;
    int lo = b << 8;
    int beg = bbase[b], end = bbase[b + 1];
    int tid = threadIdx.x, lane = tid & 63, wv = tid >> 6;
    hist[tid] = 0;
    __syncthreads();
    for (int i = beg + tid; i < end; i += 256)
        atomicAdd(&hist[pairs[i].y & 255], 1);
    __syncthreads();
    int v = hist[tid];
    int incl = v;
#pragma unroll
    for (int off = 1; off < 64; off <<= 1) {
        int t = __shfl_up(incl, off, 64);
        if (lane >= off) incl += t;
    }
    if (lane == 63) wtot[wv] = incl;
    __syncthreads();
    int wo = 0;
    for (int w = 0; w < wv; ++w) wo += wtot[w];
    int ex = wo + incl - v;   // exclusive scan within bucket
    int node = lo + tid;
    if (node < n) {
        row_ptr[node] = beg + ex;
        dinv[node] = rsqrtf((float)(v + 1));   // +1 self-loop
    }
    __syncthreads();
    hist[tid] = ex;   // reuse as cursor
    __syncthreads();
    for (int i = beg + tid; i < end; i += 256) {
        int2 p = pairs[i];
        int pos = atomicAdd(&hist[p.y & 255], 1);
        csr_src[beg + pos] = p.x;
    }
}

// ---------------------------------------------------------------------------
// Monolithic row-gather aggregation (one wave per node, lane = half2 col).
// Inner loop: wave-uniform src index via readfirstlane (scalar dinv load),
// 8-deep unroll for MLP. out = di*(di*T[i] + sum_e dinv[s]*T[s]) + bias.
// MODE 0: relu, fp16 row-major out (h). MODE 1: f32 split slabs (mu | lv).
// ---------------------------------------------------------------------------
template <int MODE>
__global__ __launch_bounds__(256) void agg_row_kernel(
    const __half* __restrict__ T, const float* __restrict__ dinv,
    const int* __restrict__ row_ptr, const int* __restrict__ csr_src,
    const float* __restrict__ bias, void* __restrict__ outa,
    void* __restrict__ outb, int n) {
    int wave = (int)((blockIdx.x * blockDim.x + threadIdx.x) >> 6);
    int lane = threadIdx.x & 63;
    if (wave >= n) return;
    const __half2* x2 = (const __half2*)T;
    float di = dinv[wave];
    float2 xf = __half22float2(x2[((size_t)wave << 6) + lane]);
    float ax = 0.f, ay = 0.f;
    int e = row_ptr[wave], end = row_ptr[wave + 1];
    for (; e + 8 <= end; e += 8) {
        int s[8];
        float w[8];
        float2 u[8];
#pragma unroll
        for (int k = 0; k < 8; ++k)
            s[k] = __builtin_amdgcn_readfirstlane(csr_src[e + k]);
#pragma unroll
        for (int k = 0; k < 8; ++k) w[k] = dinv[s[k]];
#pragma unroll
        for (int k = 0; k < 8; ++k)
            u[k] = __half22float2(x2[((size_t)s[k] << 6) + lane]);
#pragma unroll
        for (int k = 0; k < 8; ++k) {
            ax += w[k] * u[k].x;
            ay += w[k] * u[k].y;
        }
    }
    for (; e < end; ++e) {
        int s = __builtin_amdgcn_readfirstlane(csr_src[e]);
        float w = dinv[s];
        float2 u = __half22float2(x2[((size_t)s << 6) + lane]);
        ax += w * u.x;
        ay += w * u.y;
    }
    float2 bv = *(const float2*)(bias + 2 * lane);
    float vx = di * (di * xf.x + ax) + bv.x;
    float vy = di * (di * xf.y + ay) + bv.y;
    if (MODE == 0) {
        vx = fmaxf(vx, 0.f);
        vy = fmaxf(vy, 0.f);
        __half2 hv = __floats2half2_rn(vx, vy);
        unsigned int bits;
        __builtin_memcpy(&bits, &hv, 4);
        unsigned int* o = (unsigned int*)outa;
        __builtin_nontemporal_store(bits, o + ((size_t)wave << 6) + lane);
    } else {
        // cols 2*lane, 2*lane+1: lane<32 -> mu slab, lane>=32 -> lv slab
        float* o = (lane < 32) ? (float*)outa : (float*)outb;
        int cc = (2 * lane) & 63;
        f32x2 v = {vx, vy};
        __builtin_nontemporal_store(v, (f32x2*)(o + (size_t)wave * 64 + cc));
    }
}

// ---------------------------------------------------------------------------
// Pack f32 weights into fp16 MFMA B-fragment order.
// b_frag for (nt,kt) at lane l holds B[k][c], k = kt*32+(l>>4)*8+e,
// c = nt*16+(l&15). Wb==nullptr: single 128-col Wa (ld 128);
// else cols 0..63 from Wa, 64..127 from Wb (each ld 64).
// ---------------------------------------------------------------------------
__global__ void packw_kernel(const float* __restrict__ Wa,
                             const float* __restrict__ Wb,
                             __half* __restrict__ dst) {
    int t = blockIdx.x * 256 + threadIdx.x;   // 0..2047
    int lane = t & 63;
    int fk = t >> 6;          // nt*4 + kt
    int kt = fk & 3, nt = fk >> 2;
    int k0 = kt * 32 + ((lane >> 4) << 3);
    int c = nt * 16 + (lane & 15);
    const float* W;
    int ldw, cc;
    if (Wb) {
        W = (c < 64) ? Wa : Wb;
        cc = c & 63;
        ldw = 64;
    } else {
        W = Wa;
        cc = c;
        ldw = 128;
    }
    __half tmp[8];
#pragma unroll
    for (int e = 0; e < 8; ++e)
        tmp[e] = __float2half(W[(size_t)(k0 + e) * ldw + cc]);
    *(float4*)(dst + (size_t)t * 8) = *(float4*)tmp;
}

__global__ void packb_kernel(const float* __restrict__ bmu,
                             const float* __restrict__ blv,
                             float* __restrict__ bcomb) {
    int i = threadIdx.x;  // 128
    bcomb[i] = (i < 64) ? bmu[i] : blv[i - 64];
}

// ---------------------------------------------------------------------------
// Pure MFMA GEMM (no bias/relu): A [n x 128] (f32 or fp16 row-major) @
// packed Wp -> fp16 row-major out. 4 waves/block, 16-row strip per wave.
// A-frag: lane holds row (lane&15), k = kt*32+(lane>>4)*8+e
// C-frag: col = lane&15, row = (lane>>4)*4 + reg   (m89-verified)
// ---------------------------------------------------------------------------
template <typename AT>
__global__ __launch_bounds__(256) void gemm_pure_kernel(
    const AT* __restrict__ A, const __half* __restrict__ Wp,
    __half* __restrict__ outh, int n) {
    int lane = threadIdx.x & 63;
    int wv = threadIdx.x >> 6;
    int m0 = (blockIdx.x * 4 + wv) * 16;
    if (m0 >= n) return;
    int row_a = m0 + (lane & 15);
    if (row_a >= n) row_a = n - 1;              // clamp; stores guarded
    half8 afr[4];
    if constexpr (sizeof(AT) == 4) {
        const float4* Arow = (const float4*)(A + (size_t)row_a * 128);
#pragma unroll
        for (int kt = 0; kt < 4; ++kt) {
            float4 lo = Arow[kt * 8 + ((lane >> 4) << 1)];
            float4 hi = Arow[kt * 8 + ((lane >> 4) << 1) + 1];
            half8 h;
            h[0] = (_Float16)lo.x; h[1] = (_Float16)lo.y;
            h[2] = (_Float16)lo.z; h[3] = (_Float16)lo.w;
            h[4] = (_Float16)hi.x; h[5] = (_Float16)hi.y;
            h[6] = (_Float16)hi.z; h[7] = (_Float16)hi.w;
            afr[kt] = h;
        }
    } else {
        const half8* Arow = (const half8*)(A + (size_t)row_a * 128);
#pragma unroll
        for (int kt = 0; kt < 4; ++kt) afr[kt] = Arow[kt * 4 + (lane >> 4)];
    }

    const half8* Wf = (const half8*)Wp;
    int colw = lane & 15;
    int rbase = m0 + ((lane >> 4) << 2);

#pragma unroll
    for (int nt = 0; nt < 8; ++nt) {
        f32x4 acc = {0.f, 0.f, 0.f, 0.f};
#pragma unroll
        for (int kt = 0; kt < 4; ++kt)
            acc = __builtin_amdgcn_mfma_f32_16x16x32_f16(
                afr[kt], Wf[(nt * 4 + kt) * 64 + lane], acc, 0, 0, 0);
        int c = nt * 16 + colw;
#pragma unroll
        for (int e = 0; e < 4; ++e) {
            int r = rbase + e;
            if (r < n) outh[(size_t)r * 128 + c] = __float2half(acc[e]);
        }
    }
}

extern "C" void kernel_launch(void* const* d_in, const int* in_sizes, int n_in,
                              void* d_out, int out_size, void* d_ws, size_t ws_size,
                              hipStream_t stream) {
    const float* x   = (const float*)d_in[0];
    const int*   ei  = (const int*)d_in[1];
    const float* W1  = (const float*)d_in[2];
    const float* b1  = (const float*)d_in[3];
    const float* Wmu = (const float*)d_in[4];
    const float* bmu = (const float*)d_in[5];
    const float* Wlv = (const float*)d_in[6];
    const float* blv = (const float*)d_in[7];
    float* out = (float*)d_out;

    const int n = in_sizes[0] / 128;   // 100000
    const int E = in_sizes[1] / 2;     // 1600000
    const int K = (n + 255) >> 8;      // dst buckets (391, <=512)

    char* ws = (char*)d_ws;
    size_t off = 0;
    auto alloc = [&](size_t bytes) -> void* {
        void* p = ws + off;
        off += (bytes + 255) & ~(size_t)255;
        return p;
    };
    int*   mode    = (int*)alloc(256);
    int*   bcnt    = (int*)alloc((size_t)K * 4);
    int*   bbase   = (int*)alloc((size_t)(K + 1) * 4);
    int*   bcur    = (int*)alloc((size_t)K * 4);
    int*   row_ptr = (int*)alloc((size_t)(n + 1) * 4);
    float* dinv    = (float*)alloc((size_t)n * 4);
    int*   csr_src = (int*)alloc((size_t)E * 4);
    int2*  pairs   = (int2*)alloc((size_t)E * 8);
    __half* bufT   = (__half*)alloc((size_t)n * 128 * 2);  // t, then g
    __half* bufH   = (__half*)alloc((size_t)n * 128 * 2);  // h
    __half* W1p    = (__half*)alloc(128 * 128 * 2);        // packed W1
    __half* W2p    = (__half*)alloc(128 * 128 * 2);        // packed [Wmu|Wlv]
    float* bcomb   = (float*)alloc(128 * 4);               // [bmu|blv]

    hipMemsetAsync(bcnt, 0, (size_t)K * 4, stream);

    detect_kernel<<<1, 64, 0, stream>>>(ei, mode);

    int pb = (E + 4095) / 4096;
    bucket_count_kernel<<<pb, 256, 0, stream>>>(ei, E, n, mode, bcnt);
    bucket_scan_kernel<<<1, 512, 0, stream>>>(bcnt, bbase, bcur,
                                              row_ptr + n, K);
    partition_kernel<<<pb, 256, 0, stream>>>(ei, E, n, mode, bcur, pairs);
    build_kernel<<<K, 256, 0, stream>>>(pairs, bbase, row_ptr, dinv,
                                        csr_src, n);

    // Weight packing (tiny)
    packw_kernel<<<8, 256, 0, stream>>>(W1, nullptr, W1p);
    packw_kernel<<<8, 256, 0, stream>>>(Wmu, Wlv, W2p);
    packb_kernel<<<1, 128, 0, stream>>>(bmu, blv, bcomb);

    int gb = (n + 63) / 64;        // MFMA gemm blocks
    int ab = (n + 3) / 4;          // agg: 4 waves/block, 1 wave/node

    // t = x @ W1  (f32 A -> fp16 row-major)
    gemm_pure_kernel<float><<<gb, 256, 0, stream>>>(x, W1p, bufT, n);
    // h = relu(agg(t) + b1)
    agg_row_kernel<0><<<ab, 256, 0, stream>>>(bufT, dinv, row_ptr, csr_src,
                                              b1, bufH, nullptr, n);
    // g = h @ [Wmu|Wlv]
    gemm_pure_kernel<__half><<<gb, 256, 0, stream>>>(bufH, W2p, bufT, n);
    // mu / logvar = agg(g) + bias  (f32 slabs)
    agg_row_kernel<1><<<ab, 256, 0, stream>>>(bufT, dinv, row_ptr, csr_src,
                                              bcomb, out, out + (size_t)n * 64, n);
}